// Round 1
// baseline (500.586 us; speedup 1.0000x reference)
//
#include <hip/hip_runtime.h>
#include <hip/hip_bf16.h>

#define DEVI __device__ __forceinline__

typedef __bf16 bf16x8 __attribute__((ext_vector_type(8)));
typedef __bf16 bf16x4 __attribute__((ext_vector_type(4)));
typedef float f32x4 __attribute__((ext_vector_type(4)));

constexpr int B_ = 4, S_ = 2048, E_ = 1024, H_ = 16, D_ = 64;
constexpr int N_ = B_ * S_;          // 8192 tokens
constexpr float SCALE_ = 0.125f;     // 1/sqrt(64)

// ---- workspace layout (bytes) ----
// Xb  : bf16 [3][N][E]      @ 0          50331648
// Wb  : bf16 [4][E][E]      @ 50331648    8388608   (Wq,Wk,Wv,Wo)
// Qb  : bf16 [B][H][S][D]   @ 58720256   16777216
// Kb  : bf16 [B][H][S][D]   @ 75497472   16777216
// Vt  : bf16 [B][H][D][S]   @ 92274688   16777216
// Ctx : bf16 [N][E]         @ 109051904  16777216
// Lsum: f32  [B][H][S]      @ 125829120    524288
constexpr size_t XB_OFF = 0;
constexpr size_t WB_OFF = 50331648;
constexpr size_t QB_OFF = 58720256;
constexpr size_t KB_OFF = 75497472;
constexpr size_t VT_OFF = 92274688;
constexpr size_t CTX_OFF = 109051904;
constexpr size_t LS_OFF = 125829120;
constexpr size_t WS_NEED = 126353408;

typedef const __attribute__((address_space(1))) void* gas_ptr;
typedef __attribute__((address_space(3))) void* las_ptr;

DEVI void load_lds16(const void* g, void* l) {
  // async global->LDS, 16B per lane; LDS dest must be uniform-base + lane*16
  __builtin_amdgcn_global_load_lds((gas_ptr)g, (las_ptr)l, 16, 0, 0);
}

DEVI f32x4 mfma16(bf16x8 a, bf16x8 b, f32x4 c) {
  return __builtin_amdgcn_mfma_f32_16x16x32_bf16(a, b, c, 0, 0, 0);
}

// ---------------- conversion fp32 -> bf16 ----------------
__global__ __launch_bounds__(256) void conv_x(const float* __restrict__ q,
                                              const float* __restrict__ k,
                                              const float* __restrict__ v,
                                              __bf16* __restrict__ dst) {
  const float* src = (blockIdx.y == 0) ? q : ((blockIdx.y == 1) ? k : v);
  __bf16* d = dst + (size_t)blockIdx.y * N_ * E_;
  size_t i = ((size_t)blockIdx.x * blockDim.x + threadIdx.x) * 4;
  float4 f = *(const float4*)(src + i);
  bf16x4 o;
  o[0] = (__bf16)f.x; o[1] = (__bf16)f.y; o[2] = (__bf16)f.z; o[3] = (__bf16)f.w;
  *(bf16x4*)(d + i) = o;
}

__global__ __launch_bounds__(256) void conv_w(const float* __restrict__ wq,
                                              const float* __restrict__ wk,
                                              const float* __restrict__ wv,
                                              const float* __restrict__ wo,
                                              __bf16* __restrict__ dst) {
  const float* src = (blockIdx.y == 0) ? wq : ((blockIdx.y == 1) ? wk :
                     ((blockIdx.y == 2) ? wv : wo));
  __bf16* d = dst + (size_t)blockIdx.y * E_ * E_;
  size_t i = ((size_t)blockIdx.x * blockDim.x + threadIdx.x) * 4;
  float4 f = *(const float4*)(src + i);
  bf16x4 o;
  o[0] = (__bf16)f.x; o[1] = (__bf16)f.y; o[2] = (__bf16)f.z; o[3] = (__bf16)f.w;
  *(bf16x4*)(d + i) = o;
}

// ---------------- fused QKV projection GEMM ----------------
// C[m,n] = sum_k X[m,k]*W[n,k] + bias[n]; 128x128 tile, BK=32, 4 waves (2x2)
__global__ __launch_bounds__(256) void gemm_qkv(const __bf16* __restrict__ Xb,
                                                const __bf16* __restrict__ Wb,
                                                const float* __restrict__ bq,
                                                const float* __restrict__ bk,
                                                const float* __restrict__ bv,
                                                __bf16* __restrict__ Qb,
                                                __bf16* __restrict__ Kb,
                                                __bf16* __restrict__ Vt) {
  __shared__ __attribute__((aligned(16))) __bf16 As[128 * 32];
  __shared__ __attribute__((aligned(16))) __bf16 Bs[128 * 32];
  const int z = blockIdx.z;
  const __bf16* A = Xb + (size_t)z * N_ * E_;
  const __bf16* W = Wb + (size_t)z * E_ * E_;
  const float* bias = (z == 0) ? bq : ((z == 1) ? bk : bv);
  const int m0 = blockIdx.x * 128, n0 = blockIdx.y * 128;
  const int t = threadIdx.x, lane = t & 63, w = t >> 6;
  const int wm = w >> 1, wn = w & 1;

  f32x4 acc[4][4] = {};

  for (int kk = 0; kk < E_; kk += 32) {
#pragma unroll
    for (int i = 0; i < 2; ++i) {
      int c = t + i * 256;
      int row = c >> 2, kc = c & 3;
      load_lds16(A + (size_t)(m0 + row) * E_ + kk + kc * 8, (void*)(As + c * 8));
      load_lds16(W + (size_t)(n0 + row) * E_ + kk + kc * 8, (void*)(Bs + c * 8));
    }
    __syncthreads();
    bf16x8 a[4], b[4];
#pragma unroll
    for (int i = 0; i < 4; ++i)
      a[i] = *(const bf16x8*)(As + (wm * 64 + i * 16 + (lane & 15)) * 32 + ((lane >> 4) * 8));
#pragma unroll
    for (int j = 0; j < 4; ++j)
      b[j] = *(const bf16x8*)(Bs + (wn * 64 + j * 16 + (lane & 15)) * 32 + ((lane >> 4) * 8));
#pragma unroll
    for (int i = 0; i < 4; ++i)
#pragma unroll
      for (int j = 0; j < 4; ++j)
        acc[i][j] = mfma16(a[i], b[j], acc[i][j]);
    __syncthreads();
  }

  // epilogue: scatter into head-split layouts
#pragma unroll
  for (int i = 0; i < 4; ++i) {
    int mloc = wm * 64 + i * 16 + ((lane >> 4) << 2);
#pragma unroll
    for (int j = 0; j < 4; ++j) {
      int nloc = wn * 64 + j * 16 + (lane & 15);
      int n = n0 + nloc;
      int h = n >> 6, d = n & 63;
      float bs = bias[n];
      if (z == 2) {
        int m = m0 + mloc;
        int bb = m >> 11, s = m & 2047;
        bf16x4 pk;
#pragma unroll
        for (int r = 0; r < 4; ++r) pk[r] = (__bf16)(acc[i][j][r] + bs);
        *(bf16x4*)(Vt + ((size_t)(bb * H_ + h) * D_ + d) * S_ + s) = pk;
      } else {
        __bf16* dst = (z == 0) ? Qb : Kb;
#pragma unroll
        for (int r = 0; r < 4; ++r) {
          int m = m0 + mloc + r;
          int bb = m >> 11, s = m & 2047;
          dst[((size_t)(bb * H_ + h) * S_ + s) * D_ + d] = (__bf16)(acc[i][j][r] + bs);
        }
      }
    }
  }
}

// ---------------- fused attention: S=QK^T -> exp -> PV, plus row-sums l ----------------
// grid (S/128, B*H); block 256 (2x2 waves); q-tile 128, k-tile 64
__global__ __launch_bounds__(256) void attn_pv(const __bf16* __restrict__ Qb,
                                               const __bf16* __restrict__ Kb,
                                               const __bf16* __restrict__ Vt,
                                               float* __restrict__ Lsum,
                                               __bf16* __restrict__ Ctx) {
  __shared__ __attribute__((aligned(16))) __bf16 Qs[2 * 128 * 32]; // [ks][row][32]
  __shared__ __attribute__((aligned(16))) __bf16 Ks[2 * 64 * 32];  // [ks][krow][32]
  __shared__ __attribute__((aligned(16))) __bf16 Vs[2 * 64 * 32];  // [ks][d][32]
  __shared__ __attribute__((aligned(16))) __bf16 Ps[128 * 72];     // padded (+8) P tile
  __shared__ float lred[2][128];

  const int q0 = blockIdx.x * 128;
  const int bh = blockIdx.y;
  const __bf16* Qh = Qb + (size_t)bh * S_ * D_;
  const __bf16* Kh = Kb + (size_t)bh * S_ * D_;
  const __bf16* Vh = Vt + (size_t)bh * D_ * S_;
  const int t = threadIdx.x, lane = t & 63, w = t >> 6;
  const int wm = w >> 1, wn = w & 1;

  // stage Q tile once: [2][128][32], 1024 chunks of 16B
#pragma unroll
  for (int i = 0; i < 4; ++i) {
    int c = t + i * 256;
    int sub = c >> 9, rem = c & 511, row = rem >> 2, kc = rem & 3;
    load_lds16(Qh + (size_t)(q0 + row) * D_ + sub * 32 + kc * 8, (void*)(Qs + c * 8));
  }
  __syncthreads();
  bf16x8 aq[4][2];
#pragma unroll
  for (int i = 0; i < 4; ++i)
#pragma unroll
    for (int ks = 0; ks < 2; ++ks)
      aq[i][ks] = *(const bf16x8*)(Qs + ks * 4096 + (wm * 64 + i * 16 + (lane & 15)) * 32 + ((lane >> 4) * 8));

  f32x4 acc_o[4][2] = {};
  float lacc[4][4] = {};

  for (int k0 = 0; k0 < S_; k0 += 64) {
    // stage K and V tiles: [2][64][32] each, 512 chunks each
#pragma unroll
    for (int i = 0; i < 2; ++i) {
      int c = t + i * 256;
      int sub = c >> 8, rem = c & 255, row = rem >> 2, kc = rem & 3;
      load_lds16(Kh + (size_t)(k0 + row) * D_ + sub * 32 + kc * 8, (void*)(Ks + c * 8));
      load_lds16(Vh + (size_t)row * S_ + k0 + sub * 32 + kc * 8, (void*)(Vs + c * 8));
    }
    __syncthreads();

    // S phase: wave computes 64q x 32k scores
#pragma unroll
    for (int i = 0; i < 4; ++i) {
#pragma unroll
      for (int j = 0; j < 2; ++j) {
        f32x4 s = {};
#pragma unroll
        for (int ks = 0; ks < 2; ++ks) {
          bf16x8 bk_ = *(const bf16x8*)(Ks + ks * 2048 + (wn * 32 + j * 16 + (lane & 15)) * 32 + ((lane >> 4) * 8));
          s = mfma16(aq[i][ks], bk_, s);
        }
        int row = wm * 64 + i * 16 + ((lane >> 4) << 2);
        int col = wn * 32 + j * 16 + (lane & 15);
#pragma unroll
        for (int r = 0; r < 4; ++r) {
          float e = __expf(s[r] * SCALE_);
          lacc[i][r] += e;
          Ps[(row + r) * 72 + col] = (__bf16)e;
        }
      }
    }
    __syncthreads();

    // PV phase: O[128q][64d] += P[128][64] * V^T
#pragma unroll
    for (int ks = 0; ks < 2; ++ks) {
      bf16x8 ap[4];
#pragma unroll
      for (int i = 0; i < 4; ++i)
        ap[i] = *(const bf16x8*)(Ps + (size_t)(wm * 64 + i * 16 + (lane & 15)) * 72 + ks * 32 + ((lane >> 4) * 8));
#pragma unroll
      for (int j = 0; j < 2; ++j) {
        bf16x8 bv_ = *(const bf16x8*)(Vs + ks * 2048 + (wn * 32 + j * 16 + (lane & 15)) * 32 + ((lane >> 4) * 8));
#pragma unroll
        for (int i = 0; i < 4; ++i)
          acc_o[i][j] = mfma16(ap[i], bv_, acc_o[i][j]);
      }
    }
    __syncthreads();
  }

  // combine row sums across the two wn half-waves
#pragma unroll
  for (int i = 0; i < 4; ++i)
#pragma unroll
    for (int r = 0; r < 4; ++r) {
      float v = lacc[i][r];
      v += __shfl_xor(v, 1);
      v += __shfl_xor(v, 2);
      v += __shfl_xor(v, 4);
      v += __shfl_xor(v, 8);
      if ((lane & 15) == 0)
        lred[wn][wm * 64 + i * 16 + ((lane >> 4) << 2) + r] = v;
    }
  __syncthreads();

  if (t < 128)
    Lsum[(size_t)bh * S_ + q0 + t] = lred[0][t] + lred[1][t];

  const int bb = bh >> 4, h = bh & 15;
#pragma unroll
  for (int i = 0; i < 4; ++i) {
    int rowb = wm * 64 + i * 16 + ((lane >> 4) << 2);
#pragma unroll
    for (int r = 0; r < 4; ++r) {
      float invl = 1.0f / (lred[0][rowb + r] + lred[1][rowb + r]);
      int q = q0 + rowb + r;
#pragma unroll
      for (int j = 0; j < 2; ++j) {
        int d = wn * 32 + j * 16 + (lane & 15);
        Ctx[((size_t)bb * S_ + q) * E_ + h * 64 + d] = (__bf16)(acc_o[i][j][r] * invl);
      }
    }
  }
}

// ---------------- attn mean over heads: recompute S, sum_h exp(s)/l_h ----------------
// grid (S/128 kt, S/128 qt, B); block 256 (2x2 waves)
__global__ __launch_bounds__(256) void attn_mean(const __bf16* __restrict__ Qb,
                                                 const __bf16* __restrict__ Kb,
                                                 const float* __restrict__ Lsum,
                                                 float* __restrict__ meanout) {
  __shared__ __attribute__((aligned(16))) __bf16 Qs[2 * 128 * 32];
  __shared__ __attribute__((aligned(16))) __bf16 Ks2[2 * 128 * 32];
  __shared__ float Lt[128];
  const int k0 = blockIdx.x * 128, q0 = blockIdx.y * 128, bI = blockIdx.z;
  const int t = threadIdx.x, lane = t & 63, w = t >> 6;
  const int wm = w >> 1, wn = w & 1;

  float macc[4][4][4] = {};

  for (int h = 0; h < H_; ++h) {
    const size_t bh = (size_t)bI * H_ + h;
    const __bf16* Qh = Qb + bh * S_ * D_;
    const __bf16* Kh = Kb + bh * S_ * D_;
#pragma unroll
    for (int i = 0; i < 4; ++i) {
      int c = t + i * 256;
      int sub = c >> 9, rem = c & 511, row = rem >> 2, kc = rem & 3;
      load_lds16(Qh + (size_t)(q0 + row) * D_ + sub * 32 + kc * 8, (void*)(Qs + c * 8));
      load_lds16(Kh + (size_t)(k0 + row) * D_ + sub * 32 + kc * 8, (void*)(Ks2 + c * 8));
    }
    if (t < 128) Lt[t] = 1.0f / Lsum[bh * S_ + q0 + t];
    __syncthreads();

    bf16x8 a[4][2], bb[4][2];
#pragma unroll
    for (int i = 0; i < 4; ++i)
#pragma unroll
      for (int ks = 0; ks < 2; ++ks)
        a[i][ks] = *(const bf16x8*)(Qs + ks * 4096 + (wm * 64 + i * 16 + (lane & 15)) * 32 + ((lane >> 4) * 8));
#pragma unroll
    for (int j = 0; j < 4; ++j)
#pragma unroll
      for (int ks = 0; ks < 2; ++ks)
        bb[j][ks] = *(const bf16x8*)(Ks2 + ks * 4096 + (wn * 64 + j * 16 + (lane & 15)) * 32 + ((lane >> 4) * 8));

    float invl[4][4];
#pragma unroll
    for (int i = 0; i < 4; ++i) {
      int rowb = wm * 64 + i * 16 + ((lane >> 4) << 2);
#pragma unroll
      for (int r = 0; r < 4; ++r) invl[i][r] = Lt[rowb + r];
    }

#pragma unroll
    for (int i = 0; i < 4; ++i)
#pragma unroll
      for (int j = 0; j < 4; ++j) {
        f32x4 s = {};
#pragma unroll
        for (int ks = 0; ks < 2; ++ks) s = mfma16(a[i][ks], bb[j][ks], s);
#pragma unroll
        for (int r = 0; r < 4; ++r)
          macc[i][j][r] += __expf(s[r] * SCALE_) * invl[i][r];
      }
    __syncthreads();
  }

#pragma unroll
  for (int i = 0; i < 4; ++i) {
    int rowb = wm * 64 + i * 16 + ((lane >> 4) << 2);
#pragma unroll
    for (int j = 0; j < 4; ++j) {
      int col = k0 + wn * 64 + j * 16 + (lane & 15);
#pragma unroll
      for (int r = 0; r < 4; ++r)
        meanout[((size_t)bI * S_ + q0 + rowb + r) * S_ + col] = macc[i][j][r] * 0.0625f;
    }
  }
}

// ---------------- output projection GEMM ----------------
__global__ __launch_bounds__(256) void gemm_out(const __bf16* __restrict__ Ctx,
                                                const __bf16* __restrict__ Wo,
                                                const float* __restrict__ bo,
                                                float* __restrict__ out) {
  __shared__ __attribute__((aligned(16))) __bf16 As[128 * 32];
  __shared__ __attribute__((aligned(16))) __bf16 Bs[128 * 32];
  const int m0 = blockIdx.x * 128, n0 = blockIdx.y * 128;
  const int t = threadIdx.x, lane = t & 63, w = t >> 6;
  const int wm = w >> 1, wn = w & 1;

  f32x4 acc[4][4] = {};

  for (int kk = 0; kk < E_; kk += 32) {
#pragma unroll
    for (int i = 0; i < 2; ++i) {
      int c = t + i * 256;
      int row = c >> 2, kc = c & 3;
      load_lds16(Ctx + (size_t)(m0 + row) * E_ + kk + kc * 8, (void*)(As + c * 8));
      load_lds16(Wo + (size_t)(n0 + row) * E_ + kk + kc * 8, (void*)(Bs + c * 8));
    }
    __syncthreads();
    bf16x8 a[4], b[4];
#pragma unroll
    for (int i = 0; i < 4; ++i)
      a[i] = *(const bf16x8*)(As + (wm * 64 + i * 16 + (lane & 15)) * 32 + ((lane >> 4) * 8));
#pragma unroll
    for (int j = 0; j < 4; ++j)
      b[j] = *(const bf16x8*)(Bs + (wn * 64 + j * 16 + (lane & 15)) * 32 + ((lane >> 4) * 8));
#pragma unroll
    for (int i = 0; i < 4; ++i)
#pragma unroll
      for (int j = 0; j < 4; ++j)
        acc[i][j] = mfma16(a[i], b[j], acc[i][j]);
    __syncthreads();
  }

#pragma unroll
  for (int i = 0; i < 4; ++i) {
    int mloc = wm * 64 + i * 16 + ((lane >> 4) << 2);
#pragma unroll
    for (int j = 0; j < 4; ++j) {
      int n = n0 + wn * 64 + j * 16 + (lane & 15);
      float bs = bo[n];
#pragma unroll
      for (int r = 0; r < 4; ++r)
        out[(size_t)(m0 + mloc + r) * E_ + n] = acc[i][j][r] + bs;
    }
  }
}

extern "C" void kernel_launch(void* const* d_in, const int* in_sizes, int n_in,
                              void* d_out, int out_size, void* d_ws, size_t ws_size,
                              hipStream_t stream) {
  if (ws_size < WS_NEED) {
    // workspace too small for this implementation: emit clean zeros so the
    // failure mode is diagnosable (absmax == max|ref|) rather than a fault
    hipMemsetAsync(d_out, 0, (size_t)out_size * sizeof(float), stream);
    return;
  }

  const float* q  = (const float*)d_in[0];
  const float* k  = (const float*)d_in[1];
  const float* v  = (const float*)d_in[2];
  const float* Wq = (const float*)d_in[3];
  const float* bq = (const float*)d_in[4];
  const float* Wk = (const float*)d_in[5];
  const float* bk = (const float*)d_in[6];
  const float* Wv = (const float*)d_in[7];
  const float* bv = (const float*)d_in[8];
  const float* Wo = (const float*)d_in[9];
  const float* bo = (const float*)d_in[10];

  char* ws = (char*)d_ws;
  __bf16* Xb  = (__bf16*)(ws + XB_OFF);
  __bf16* Wb  = (__bf16*)(ws + WB_OFF);
  __bf16* Qb  = (__bf16*)(ws + QB_OFF);
  __bf16* Kb  = (__bf16*)(ws + KB_OFF);
  __bf16* Vt  = (__bf16*)(ws + VT_OFF);
  __bf16* Ctx = (__bf16*)(ws + CTX_OFF);
  float*  Ls  = (float*)(ws + LS_OFF);

  float* out0 = (float*)d_out;                    // [B,S,E]
  float* out1 = (float*)d_out + (size_t)N_ * E_;  // [B,S,S]

  conv_x<<<dim3(N_ * E_ / 4 / 256, 3), 256, 0, stream>>>(q, k, v, Xb);
  conv_w<<<dim3(E_ * E_ / 4 / 256, 4), 256, 0, stream>>>(Wq, Wk, Wv, Wo, Wb);
  gemm_qkv<<<dim3(N_ / 128, E_ / 128, 3), 256, 0, stream>>>(Xb, Wb, bq, bk, bv, Qb, Kb, Vt);
  attn_pv<<<dim3(S_ / 128, B_ * H_), 256, 0, stream>>>(Qb, Kb, Vt, Ls, Ctx);
  attn_mean<<<dim3(S_ / 128, S_ / 128, B_), 256, 0, stream>>>(Qb, Kb, Ls, out1);
  gemm_out<<<dim3(N_ / 128, E_ / 128), 256, 0, stream>>>(Ctx, Wb + 3 * (size_t)E_ * E_, bo, out0);
}

// Round 2
// 439.250 us; speedup vs baseline: 1.1396x; 1.1396x over previous
//
#include <hip/hip_runtime.h>
#include <hip/hip_bf16.h>

#define DEVI __device__ __forceinline__

typedef __bf16 bf16x8 __attribute__((ext_vector_type(8)));
typedef __bf16 bf16x4 __attribute__((ext_vector_type(4)));
typedef float f32x4 __attribute__((ext_vector_type(4)));

constexpr int B_ = 4, S_ = 2048, E_ = 1024, H_ = 16, D_ = 64;
constexpr int N_ = B_ * S_;          // 8192 tokens
constexpr float SCALE_ = 0.125f;     // 1/sqrt(64)

// ---- workspace layout (bytes) ----
constexpr size_t XB_OFF = 0;           // bf16 [3][N][E]
constexpr size_t WB_OFF = 50331648;    // bf16 [4][E][E]
constexpr size_t QB_OFF = 58720256;    // bf16 [B][H][S][D]
constexpr size_t KB_OFF = 75497472;    // bf16 [B][H][S][D]
constexpr size_t VT_OFF = 92274688;    // bf16 [B][H][D][S]
constexpr size_t CTX_OFF = 109051904;  // bf16 [N][E]
constexpr size_t LS_OFF = 125829120;   // f32  [B][H][S]
constexpr size_t WS_NEED = 126353408;

typedef const __attribute__((address_space(1))) void* gas_ptr;
typedef __attribute__((address_space(3))) void* las_ptr;

DEVI void load_lds16(const void* g, void* l) {
  __builtin_amdgcn_global_load_lds((gas_ptr)g, (las_ptr)l, 16, 0, 0);
}

DEVI f32x4 mfma16(bf16x8 a, bf16x8 b, f32x4 c) {
  return __builtin_amdgcn_mfma_f32_16x16x32_bf16(a, b, c, 0, 0, 0);
}

// ---------------- conversion fp32 -> bf16 ----------------
__global__ __launch_bounds__(256) void conv_x(const float* __restrict__ q,
                                              const float* __restrict__ k,
                                              const float* __restrict__ v,
                                              __bf16* __restrict__ dst) {
  const float* src = (blockIdx.y == 0) ? q : ((blockIdx.y == 1) ? k : v);
  __bf16* d = dst + (size_t)blockIdx.y * N_ * E_;
  size_t i = ((size_t)blockIdx.x * blockDim.x + threadIdx.x) * 4;
  float4 f = *(const float4*)(src + i);
  bf16x4 o;
  o[0] = (__bf16)f.x; o[1] = (__bf16)f.y; o[2] = (__bf16)f.z; o[3] = (__bf16)f.w;
  *(bf16x4*)(d + i) = o;
}

__global__ __launch_bounds__(256) void conv_w(const float* __restrict__ wq,
                                              const float* __restrict__ wk,
                                              const float* __restrict__ wv,
                                              const float* __restrict__ wo,
                                              __bf16* __restrict__ dst) {
  const float* src = (blockIdx.y == 0) ? wq : ((blockIdx.y == 1) ? wk :
                     ((blockIdx.y == 2) ? wv : wo));
  __bf16* d = dst + (size_t)blockIdx.y * E_ * E_;
  size_t i = ((size_t)blockIdx.x * blockDim.x + threadIdx.x) * 4;
  float4 f = *(const float4*)(src + i);
  bf16x4 o;
  o[0] = (__bf16)f.x; o[1] = (__bf16)f.y; o[2] = (__bf16)f.z; o[3] = (__bf16)f.w;
  *(bf16x4*)(d + i) = o;
}

// ---------------- fused QKV projection GEMM ----------------
__global__ __launch_bounds__(256) void gemm_qkv(const __bf16* __restrict__ Xb,
                                                const __bf16* __restrict__ Wb,
                                                const float* __restrict__ bq,
                                                const float* __restrict__ bk,
                                                const float* __restrict__ bv,
                                                __bf16* __restrict__ Qb,
                                                __bf16* __restrict__ Kb,
                                                __bf16* __restrict__ Vt) {
  __shared__ __attribute__((aligned(16))) __bf16 As[128 * 32];
  __shared__ __attribute__((aligned(16))) __bf16 Bs[128 * 32];
  const int z = blockIdx.z;
  const __bf16* A = Xb + (size_t)z * N_ * E_;
  const __bf16* W = Wb + (size_t)z * E_ * E_;
  const float* bias = (z == 0) ? bq : ((z == 1) ? bk : bv);
  const int m0 = blockIdx.x * 128, n0 = blockIdx.y * 128;
  const int t = threadIdx.x, lane = t & 63, w = t >> 6;
  const int wm = w >> 1, wn = w & 1;

  f32x4 acc[4][4] = {};

  for (int kk = 0; kk < E_; kk += 32) {
#pragma unroll
    for (int i = 0; i < 2; ++i) {
      int c = t + i * 256;
      int row = c >> 2, kc = c & 3;
      load_lds16(A + (size_t)(m0 + row) * E_ + kk + kc * 8, (void*)(As + c * 8));
      load_lds16(W + (size_t)(n0 + row) * E_ + kk + kc * 8, (void*)(Bs + c * 8));
    }
    __syncthreads();
    bf16x8 a[4], b[4];
#pragma unroll
    for (int i = 0; i < 4; ++i)
      a[i] = *(const bf16x8*)(As + (wm * 64 + i * 16 + (lane & 15)) * 32 + ((lane >> 4) * 8));
#pragma unroll
    for (int j = 0; j < 4; ++j)
      b[j] = *(const bf16x8*)(Bs + (wn * 64 + j * 16 + (lane & 15)) * 32 + ((lane >> 4) * 8));
#pragma unroll
    for (int i = 0; i < 4; ++i)
#pragma unroll
      for (int j = 0; j < 4; ++j)
        acc[i][j] = mfma16(a[i], b[j], acc[i][j]);
    __syncthreads();
  }

#pragma unroll
  for (int i = 0; i < 4; ++i) {
    int mloc = wm * 64 + i * 16 + ((lane >> 4) << 2);
#pragma unroll
    for (int j = 0; j < 4; ++j) {
      int nloc = wn * 64 + j * 16 + (lane & 15);
      int n = n0 + nloc;
      int h = n >> 6, d = n & 63;
      float bs = bias[n];
      if (z == 2) {
        int m = m0 + mloc;
        int bb = m >> 11, s = m & 2047;
        bf16x4 pk;
#pragma unroll
        for (int r = 0; r < 4; ++r) pk[r] = (__bf16)(acc[i][j][r] + bs);
        *(bf16x4*)(Vt + ((size_t)(bb * H_ + h) * D_ + d) * S_ + s) = pk;
      } else {
        __bf16* dst = (z == 0) ? Qb : Kb;
#pragma unroll
        for (int r = 0; r < 4; ++r) {
          int m = m0 + mloc + r;
          int bb = m >> 11, s = m & 2047;
          dst[((size_t)(bb * H_ + h) * S_ + s) * D_ + d] = (__bf16)(acc[i][j][r] + bs);
        }
      }
    }
  }
}

// ---------------- fused attention via S^T: no P transpose ----------------
// Computes S^T = K*Q^T with interleaved k-row mapping so exp'd C fragments ARE
// the B-operand of O^T = Vt*P^T. l comes from a ones-MFMA (every lane holds its
// own q's denominator). grid (S/128, B*H); 4 waves; wave owns 32 q columns.
__global__ __launch_bounds__(256, 4) void attn_pv(const __bf16* __restrict__ Qb,
                                                  const __bf16* __restrict__ Kb,
                                                  const __bf16* __restrict__ Vt,
                                                  float* __restrict__ Lsum,
                                                  __bf16* __restrict__ Ctx) {
  __shared__ __attribute__((aligned(16))) __bf16 Qs[2 * 128 * 32]; // [ks][q][32]
  __shared__ __attribute__((aligned(16))) __bf16 Ks[2 * 64 * 32];  // [ks][k][32]
  __shared__ __attribute__((aligned(16))) __bf16 Vs[2 * 64 * 32];  // [kchunk][d][32]

  const int q0 = blockIdx.x * 128;
  const int bh = blockIdx.y;
  const __bf16* Qh = Qb + (size_t)bh * S_ * D_;
  const __bf16* Kh = Kb + (size_t)bh * S_ * D_;
  const __bf16* Vh = Vt + (size_t)bh * D_ * S_;
  const int t = threadIdx.x, lane = t & 63, w = t >> 6;
  const int l15 = lane & 15, ghi8 = (lane >> 4) * 8;
  // interleaved m->k mapping: k_local = 8*(m>>2) + 4*blk + (m&3)
  const int ksel = 8 * (l15 >> 2) + (l15 & 3);

  // stage Q tile once: [2][128][32]
#pragma unroll
  for (int i = 0; i < 4; ++i) {
    int c = t + i * 256;
    int sub = c >> 9, rem = c & 511, row = rem >> 2, kc = rem & 3;
    load_lds16(Qh + (size_t)(q0 + row) * D_ + sub * 32 + kc * 8, (void*)(Qs + c * 8));
  }
  __syncthreads();
  bf16x8 qf[2][2]; // [jb][ks]
#pragma unroll
  for (int jb = 0; jb < 2; ++jb)
#pragma unroll
    for (int ks = 0; ks < 2; ++ks)
      qf[jb][ks] = *(const bf16x8*)(Qs + ks * 4096 + (w * 32 + jb * 16 + l15) * 32 + ghi8);

  bf16x8 ones;
#pragma unroll
  for (int i = 0; i < 8; ++i) ones[i] = (__bf16)1.0f;

  f32x4 acc[4][2] = {};  // [d-block][jb] — O^T tile
  f32x4 lacc[2] = {};    // denominator via ones-MFMA

  for (int k0 = 0; k0 < S_; k0 += 64) {
#pragma unroll
    for (int i = 0; i < 2; ++i) {
      int c = t + i * 256;
      int sub = c >> 8, rem = c & 255, row = rem >> 2, kc = rem & 3;
      load_lds16(Kh + (size_t)(k0 + row) * D_ + sub * 32 + kc * 8, (void*)(Ks + c * 8));
      load_lds16(Vh + (size_t)row * S_ + k0 + sub * 32 + kc * 8, (void*)(Vs + c * 8));
    }
    __syncthreads();

#pragma unroll
    for (int chunk = 0; chunk < 2; ++chunk) {
      f32x4 sc[2][2]; // [blk][jb]
#pragma unroll
      for (int blk = 0; blk < 2; ++blk) {
        int krow = chunk * 32 + 4 * blk + ksel;
        bf16x8 kf0 = *(const bf16x8*)(Ks + krow * 32 + ghi8);
        bf16x8 kf1 = *(const bf16x8*)(Ks + 2048 + krow * 32 + ghi8);
#pragma unroll
        for (int jb = 0; jb < 2; ++jb) {
          f32x4 s = {};
          s = mfma16(kf0, qf[jb][0], s);
          s = mfma16(kf1, qf[jb][1], s);
          sc[blk][jb] = s;
        }
      }
      bf16x8 pf[2];
#pragma unroll
      for (int jb = 0; jb < 2; ++jb) {
#pragma unroll
        for (int r = 0; r < 4; ++r) {
          pf[jb][r]     = (__bf16)__expf(sc[0][jb][r] * SCALE_);
          pf[jb][4 + r] = (__bf16)__expf(sc[1][jb][r] * SCALE_);
        }
        lacc[jb] = mfma16(ones, pf[jb], lacc[jb]);
      }
#pragma unroll
      for (int mb = 0; mb < 4; ++mb) {
        bf16x8 vf = *(const bf16x8*)(Vs + chunk * 2048 + (mb * 16 + l15) * 32 + ghi8);
#pragma unroll
        for (int jb = 0; jb < 2; ++jb)
          acc[mb][jb] = mfma16(vf, pf[jb], acc[mb][jb]);
      }
    }
    __syncthreads();
  }

  // every lane holds l for its own q column in lacc[jb][0]
  if (lane < 16) {
#pragma unroll
    for (int jb = 0; jb < 2; ++jb)
      Lsum[(size_t)bh * S_ + q0 + w * 32 + jb * 16 + lane] = lacc[jb][0];
  }

  const int bb = bh >> 4, h = bh & 15;
#pragma unroll
  for (int jb = 0; jb < 2; ++jb) {
    float invl = 1.0f / lacc[jb][0];
    int q = q0 + w * 32 + jb * 16 + l15;
#pragma unroll
    for (int mb = 0; mb < 4; ++mb) {
      int d = mb * 16 + ((lane >> 4) << 2);
      bf16x4 pk;
#pragma unroll
      for (int r = 0; r < 4; ++r) pk[r] = (__bf16)(acc[mb][jb][r] * invl);
      *(bf16x4*)(Ctx + ((size_t)bb * S_ + q) * E_ + h * 64 + d) = pk;
    }
  }
}

// ---------------- attn mean over heads (S^T recompute) ----------------
// grid (S/128 kt, S/128 qt, B); wave owns 32 q cols x 128 k rows.
__global__ __launch_bounds__(256, 4) void attn_mean(const __bf16* __restrict__ Qb,
                                                    const __bf16* __restrict__ Kb,
                                                    const float* __restrict__ Lsum,
                                                    float* __restrict__ meanout) {
  __shared__ __attribute__((aligned(16))) __bf16 Qs[2 * 128 * 32];
  __shared__ __attribute__((aligned(16))) __bf16 Ks2[2 * 128 * 32];
  const int k0 = blockIdx.x * 128, q0 = blockIdx.y * 128, bI = blockIdx.z;
  const int t = threadIdx.x, lane = t & 63, w = t >> 6;
  const int l15 = lane & 15, ghi8 = (lane >> 4) * 8;
  const int ksel = 8 * (l15 >> 2) + (l15 & 3);

  f32x4 macc[4][2][2] = {}; // [chunk][blk][jb]

  for (int h = 0; h < H_; ++h) {
    const size_t bh = (size_t)bI * H_ + h;
    const __bf16* Qh = Qb + bh * S_ * D_;
    const __bf16* Kh = Kb + bh * S_ * D_;
#pragma unroll
    for (int i = 0; i < 4; ++i) {
      int c = t + i * 256;
      int sub = c >> 9, rem = c & 511, row = rem >> 2, kc = rem & 3;
      load_lds16(Qh + (size_t)(q0 + row) * D_ + sub * 32 + kc * 8, (void*)(Qs + c * 8));
      load_lds16(Kh + (size_t)(k0 + row) * D_ + sub * 32 + kc * 8, (void*)(Ks2 + c * 8));
    }
    float invl[2];
#pragma unroll
    for (int jb = 0; jb < 2; ++jb)
      invl[jb] = 1.0f / Lsum[bh * S_ + q0 + w * 32 + jb * 16 + l15];
    __syncthreads();

    bf16x8 qf[2][2];
#pragma unroll
    for (int jb = 0; jb < 2; ++jb)
#pragma unroll
      for (int ks = 0; ks < 2; ++ks)
        qf[jb][ks] = *(const bf16x8*)(Qs + ks * 4096 + (w * 32 + jb * 16 + l15) * 32 + ghi8);

#pragma unroll
    for (int chunk = 0; chunk < 4; ++chunk) {
#pragma unroll
      for (int blk = 0; blk < 2; ++blk) {
        int krow = chunk * 32 + 4 * blk + ksel;
        bf16x8 kf0 = *(const bf16x8*)(Ks2 + krow * 32 + ghi8);
        bf16x8 kf1 = *(const bf16x8*)(Ks2 + 4096 + krow * 32 + ghi8);
#pragma unroll
        for (int jb = 0; jb < 2; ++jb) {
          f32x4 s = {};
          s = mfma16(kf0, qf[jb][0], s);
          s = mfma16(kf1, qf[jb][1], s);
#pragma unroll
          for (int r = 0; r < 4; ++r)
            macc[chunk][blk][jb][r] += __expf(s[r] * SCALE_) * invl[jb];
        }
      }
    }
    __syncthreads();
  }

#pragma unroll
  for (int chunk = 0; chunk < 4; ++chunk)
#pragma unroll
    for (int blk = 0; blk < 2; ++blk)
#pragma unroll
      for (int jb = 0; jb < 2; ++jb) {
        int q = q0 + w * 32 + jb * 16 + l15;
        int kb = k0 + chunk * 32 + 8 * (lane >> 4) + 4 * blk;
        f32x4 o;
#pragma unroll
        for (int r = 0; r < 4; ++r) o[r] = macc[chunk][blk][jb][r] * 0.0625f;
        *(f32x4*)(meanout + ((size_t)bI * S_ + q) * S_ + kb) = o;
      }
}

// ---------------- output projection GEMM ----------------
__global__ __launch_bounds__(256) void gemm_out(const __bf16* __restrict__ Ctx,
                                                const __bf16* __restrict__ Wo,
                                                const float* __restrict__ bo,
                                                float* __restrict__ out) {
  __shared__ __attribute__((aligned(16))) __bf16 As[128 * 32];
  __shared__ __attribute__((aligned(16))) __bf16 Bs[128 * 32];
  const int m0 = blockIdx.x * 128, n0 = blockIdx.y * 128;
  const int t = threadIdx.x, lane = t & 63, w = t >> 6;
  const int wm = w >> 1, wn = w & 1;

  f32x4 acc[4][4] = {};

  for (int kk = 0; kk < E_; kk += 32) {
#pragma unroll
    for (int i = 0; i < 2; ++i) {
      int c = t + i * 256;
      int row = c >> 2, kc = c & 3;
      load_lds16(Ctx + (size_t)(m0 + row) * E_ + kk + kc * 8, (void*)(As + c * 8));
      load_lds16(Wo + (size_t)(n0 + row) * E_ + kk + kc * 8, (void*)(Bs + c * 8));
    }
    __syncthreads();
    bf16x8 a[4], b[4];
#pragma unroll
    for (int i = 0; i < 4; ++i)
      a[i] = *(const bf16x8*)(As + (wm * 64 + i * 16 + (lane & 15)) * 32 + ((lane >> 4) * 8));
#pragma unroll
    for (int j = 0; j < 4; ++j)
      b[j] = *(const bf16x8*)(Bs + (wn * 64 + j * 16 + (lane & 15)) * 32 + ((lane >> 4) * 8));
#pragma unroll
    for (int i = 0; i < 4; ++i)
#pragma unroll
      for (int j = 0; j < 4; ++j)
        acc[i][j] = mfma16(a[i], b[j], acc[i][j]);
    __syncthreads();
  }

#pragma unroll
  for (int i = 0; i < 4; ++i) {
    int mloc = wm * 64 + i * 16 + ((lane >> 4) << 2);
#pragma unroll
    for (int j = 0; j < 4; ++j) {
      int n = n0 + wn * 64 + j * 16 + (lane & 15);
      float bs = bo[n];
#pragma unroll
      for (int r = 0; r < 4; ++r)
        out[(size_t)(m0 + mloc + r) * E_ + n] = acc[i][j][r] + bs;
    }
  }
}

extern "C" void kernel_launch(void* const* d_in, const int* in_sizes, int n_in,
                              void* d_out, int out_size, void* d_ws, size_t ws_size,
                              hipStream_t stream) {
  if (ws_size < WS_NEED) {
    hipMemsetAsync(d_out, 0, (size_t)out_size * sizeof(float), stream);
    return;
  }

  const float* q  = (const float*)d_in[0];
  const float* k  = (const float*)d_in[1];
  const float* v  = (const float*)d_in[2];
  const float* Wq = (const float*)d_in[3];
  const float* bq = (const float*)d_in[4];
  const float* Wk = (const float*)d_in[5];
  const float* bk = (const float*)d_in[6];
  const float* Wv = (const float*)d_in[7];
  const float* bv = (const float*)d_in[8];
  const float* Wo = (const float*)d_in[9];
  const float* bo = (const float*)d_in[10];

  char* ws = (char*)d_ws;
  __bf16* Xb  = (__bf16*)(ws + XB_OFF);
  __bf16* Wb  = (__bf16*)(ws + WB_OFF);
  __bf16* Qb  = (__bf16*)(ws + QB_OFF);
  __bf16* Kb  = (__bf16*)(ws + KB_OFF);
  __bf16* Vt  = (__bf16*)(ws + VT_OFF);
  __bf16* Ctx = (__bf16*)(ws + CTX_OFF);
  float*  Ls  = (float*)(ws + LS_OFF);

  float* out0 = (float*)d_out;
  float* out1 = (float*)d_out + (size_t)N_ * E_;

  conv_x<<<dim3(N_ * E_ / 4 / 256, 3), 256, 0, stream>>>(q, k, v, Xb);
  conv_w<<<dim3(E_ * E_ / 4 / 256, 4), 256, 0, stream>>>(Wq, Wk, Wv, Wo, Wb);
  gemm_qkv<<<dim3(N_ / 128, E_ / 128, 3), 256, 0, stream>>>(Xb, Wb, bq, bk, bv, Qb, Kb, Vt);
  attn_pv<<<dim3(S_ / 128, B_ * H_), 256, 0, stream>>>(Qb, Kb, Vt, Ls, Ctx);
  attn_mean<<<dim3(S_ / 128, S_ / 128, B_), 256, 0, stream>>>(Qb, Kb, Ls, out1);
  gemm_out<<<dim3(N_ / 128, E_ / 128), 256, 0, stream>>>(Ctx, Wb + 3 * (size_t)E_ * E_, bo, out0);
}

// Round 3
// 435.443 us; speedup vs baseline: 1.1496x; 1.0087x over previous
//
#include <hip/hip_runtime.h>
#include <hip/hip_bf16.h>

#define DEVI __device__ __forceinline__

typedef __bf16 bf16x8 __attribute__((ext_vector_type(8)));
typedef __bf16 bf16x4 __attribute__((ext_vector_type(4)));
typedef float f32x4 __attribute__((ext_vector_type(4)));

constexpr int B_ = 4, S_ = 2048, E_ = 1024, H_ = 16, D_ = 64;
constexpr int N_ = B_ * S_;          // 8192 tokens
constexpr float SC2_ = 0.18033688011112042f;  // (1/sqrt(64)) * log2(e)

// ---- workspace layout (bytes) ----
constexpr size_t XB_OFF = 0;           // bf16 [3][N][E]
constexpr size_t WB_OFF = 50331648;    // bf16 [4][E][E]
constexpr size_t QB_OFF = 58720256;    // bf16 [B][H][S][D]
constexpr size_t KB_OFF = 75497472;    // bf16 [B][H][S][D]
constexpr size_t VT_OFF = 92274688;    // bf16 [B][H][D][S]
constexpr size_t CTX_OFF = 109051904;  // bf16 [N][E]
constexpr size_t LS_OFF = 125829120;   // f32  [B][H][S]
constexpr size_t WS_NEED = 126353408;

typedef const __attribute__((address_space(1))) void* gas_ptr;
typedef __attribute__((address_space(3))) void* las_ptr;

DEVI void load_lds16(const void* g, void* l) {
  __builtin_amdgcn_global_load_lds((gas_ptr)g, (las_ptr)l, 16, 0, 0);
}

DEVI f32x4 mfma16(bf16x8 a, bf16x8 b, f32x4 c) {
  return __builtin_amdgcn_mfma_f32_16x16x32_bf16(a, b, c, 0, 0, 0);
}

// xor-swizzle key: 16B slot permutation per row, kills bank-position aliasing
DEVI int swz(int row) { return ((row >> 1) ^ (row >> 3)) & 3; }

#if __has_builtin(__builtin_amdgcn_exp2f)
DEVI float ex2(float x) { return __builtin_amdgcn_exp2f(x); }
#else
DEVI float ex2(float x) { return exp2f(x); }
#endif

// ---------------- conversion fp32 -> bf16 ----------------
__global__ __launch_bounds__(256) void conv_x(const float* __restrict__ q,
                                              const float* __restrict__ k,
                                              const float* __restrict__ v,
                                              __bf16* __restrict__ dst) {
  const float* src = (blockIdx.y == 0) ? q : ((blockIdx.y == 1) ? k : v);
  __bf16* d = dst + (size_t)blockIdx.y * N_ * E_;
  size_t i = ((size_t)blockIdx.x * blockDim.x + threadIdx.x) * 4;
  float4 f = *(const float4*)(src + i);
  bf16x4 o;
  o[0] = (__bf16)f.x; o[1] = (__bf16)f.y; o[2] = (__bf16)f.z; o[3] = (__bf16)f.w;
  *(bf16x4*)(d + i) = o;
}

__global__ __launch_bounds__(256) void conv_w(const float* __restrict__ wq,
                                              const float* __restrict__ wk,
                                              const float* __restrict__ wv,
                                              const float* __restrict__ wo,
                                              __bf16* __restrict__ dst) {
  const float* src = (blockIdx.y == 0) ? wq : ((blockIdx.y == 1) ? wk :
                     ((blockIdx.y == 2) ? wv : wo));
  __bf16* d = dst + (size_t)blockIdx.y * E_ * E_;
  size_t i = ((size_t)blockIdx.x * blockDim.x + threadIdx.x) * 4;
  float4 f = *(const float4*)(src + i);
  bf16x4 o;
  o[0] = (__bf16)f.x; o[1] = (__bf16)f.y; o[2] = (__bf16)f.z; o[3] = (__bf16)f.w;
  *(bf16x4*)(d + i) = o;
}

// ---------------- fused QKV projection GEMM ----------------
__global__ __launch_bounds__(256) void gemm_qkv(const __bf16* __restrict__ Xb,
                                                const __bf16* __restrict__ Wb,
                                                const float* __restrict__ bq,
                                                const float* __restrict__ bk,
                                                const float* __restrict__ bv,
                                                __bf16* __restrict__ Qb,
                                                __bf16* __restrict__ Kb,
                                                __bf16* __restrict__ Vt) {
  __shared__ __attribute__((aligned(16))) __bf16 As[128 * 32];
  __shared__ __attribute__((aligned(16))) __bf16 Bs[128 * 32];
  const int z = blockIdx.z;
  const __bf16* A = Xb + (size_t)z * N_ * E_;
  const __bf16* W = Wb + (size_t)z * E_ * E_;
  const float* bias = (z == 0) ? bq : ((z == 1) ? bk : bv);
  const int m0 = blockIdx.x * 128, n0 = blockIdx.y * 128;
  const int t = threadIdx.x, lane = t & 63, w = t >> 6;
  const int wm = w >> 1, wn = w & 1;
  const int l15 = lane & 15, g = lane >> 4;

  f32x4 acc[4][4] = {};

  for (int kk = 0; kk < E_; kk += 32) {
#pragma unroll
    for (int i = 0; i < 2; ++i) {
      int c = t + i * 256;
      int row = c >> 2, kc = c & 3;
      int sl = kc ^ swz(row);
      load_lds16(A + (size_t)(m0 + row) * E_ + kk + sl * 8, (void*)(As + c * 8));
      load_lds16(W + (size_t)(n0 + row) * E_ + kk + sl * 8, (void*)(Bs + c * 8));
    }
    __syncthreads();
    bf16x8 a[4], b[4];
#pragma unroll
    for (int i = 0; i < 4; ++i) {
      int row = wm * 64 + i * 16 + l15;
      a[i] = *(const bf16x8*)(As + row * 32 + (g ^ swz(row)) * 8);
    }
#pragma unroll
    for (int j = 0; j < 4; ++j) {
      int row = wn * 64 + j * 16 + l15;
      b[j] = *(const bf16x8*)(Bs + row * 32 + (g ^ swz(row)) * 8);
    }
#pragma unroll
    for (int i = 0; i < 4; ++i)
#pragma unroll
      for (int j = 0; j < 4; ++j)
        acc[i][j] = mfma16(a[i], b[j], acc[i][j]);
    __syncthreads();
  }

#pragma unroll
  for (int i = 0; i < 4; ++i) {
    int mloc = wm * 64 + i * 16 + (g << 2);
#pragma unroll
    for (int j = 0; j < 4; ++j) {
      int nloc = wn * 64 + j * 16 + l15;
      int n = n0 + nloc;
      int h = n >> 6, d = n & 63;
      float bs = bias[n];
      if (z == 2) {
        int m = m0 + mloc;
        int bb = m >> 11, s = m & 2047;
        bf16x4 pk;
#pragma unroll
        for (int r = 0; r < 4; ++r) pk[r] = (__bf16)(acc[i][j][r] + bs);
        *(bf16x4*)(Vt + ((size_t)(bb * H_ + h) * D_ + d) * S_ + s) = pk;
      } else {
        __bf16* dst = (z == 0) ? Qb : Kb;
#pragma unroll
        for (int r = 0; r < 4; ++r) {
          int m = m0 + mloc + r;
          int bb = m >> 11, s = m & 2047;
          dst[((size_t)(bb * H_ + h) * S_ + s) * D_ + d] = (__bf16)(acc[i][j][r] + bs);
        }
      }
    }
  }
}

// ---------------- fused attention via S^T: no P transpose ----------------
__global__ __launch_bounds__(256, 4) void attn_pv(const __bf16* __restrict__ Qb,
                                                  const __bf16* __restrict__ Kb,
                                                  const __bf16* __restrict__ Vt,
                                                  float* __restrict__ Lsum,
                                                  __bf16* __restrict__ Ctx) {
  __shared__ __attribute__((aligned(16))) __bf16 Qs[2 * 128 * 32]; // [ks][q][32]
  __shared__ __attribute__((aligned(16))) __bf16 Ks[2 * 64 * 32];  // [ks][k][32]
  __shared__ __attribute__((aligned(16))) __bf16 Vs[2 * 64 * 32];  // [kchunk][d][32]

  const int q0 = blockIdx.x * 128;
  const int bh = blockIdx.y;
  const __bf16* Qh = Qb + (size_t)bh * S_ * D_;
  const __bf16* Kh = Kb + (size_t)bh * S_ * D_;
  const __bf16* Vh = Vt + (size_t)bh * D_ * S_;
  const int t = threadIdx.x, lane = t & 63, w = t >> 6;
  const int l15 = lane & 15, g = lane >> 4;
  // interleaved m->k mapping: k_local = 8*(m>>2) + 4*blk + (m&3)
  const int ksel = 8 * (l15 >> 2) + (l15 & 3);

  // stage Q tile once: [2][128][32]
#pragma unroll
  for (int i = 0; i < 4; ++i) {
    int c = t + i * 256;
    int sub = c >> 9, rem = c & 511, row = rem >> 2, kc = rem & 3;
    int sl = kc ^ swz(row);
    load_lds16(Qh + (size_t)(q0 + row) * D_ + sub * 32 + sl * 8, (void*)(Qs + c * 8));
  }
  __syncthreads();
  bf16x8 qf[2][2]; // [jb][ks]
#pragma unroll
  for (int jb = 0; jb < 2; ++jb) {
    int row = w * 32 + jb * 16 + l15;
#pragma unroll
    for (int ks = 0; ks < 2; ++ks)
      qf[jb][ks] = *(const bf16x8*)(Qs + ks * 4096 + row * 32 + (g ^ swz(row)) * 8);
  }

  bf16x8 ones;
#pragma unroll
  for (int i = 0; i < 8; ++i) ones[i] = (__bf16)1.0f;

  f32x4 acc[4][2] = {};  // [d-block][jb] — O^T tile
  f32x4 lacc[2] = {};    // denominator via ones-MFMA

  for (int k0 = 0; k0 < S_; k0 += 64) {
#pragma unroll
    for (int i = 0; i < 2; ++i) {
      int c = t + i * 256;
      int sub = c >> 8, rem = c & 255, row = rem >> 2, kc = rem & 3;
      int sl = kc ^ swz(row);
      load_lds16(Kh + (size_t)(k0 + row) * D_ + sub * 32 + sl * 8, (void*)(Ks + c * 8));
      load_lds16(Vh + (size_t)row * S_ + k0 + sub * 32 + sl * 8, (void*)(Vs + c * 8));
    }
    __syncthreads();

#pragma unroll
    for (int chunk = 0; chunk < 2; ++chunk) {
      f32x4 sc[2][2]; // [blk][jb]
#pragma unroll
      for (int blk = 0; blk < 2; ++blk) {
        int krow = chunk * 32 + 4 * blk + ksel;
        int so = (g ^ swz(krow)) * 8;
        bf16x8 kf0 = *(const bf16x8*)(Ks + krow * 32 + so);
        bf16x8 kf1 = *(const bf16x8*)(Ks + 2048 + krow * 32 + so);
#pragma unroll
        for (int jb = 0; jb < 2; ++jb) {
          f32x4 s = {};
          s = mfma16(kf0, qf[jb][0], s);
          s = mfma16(kf1, qf[jb][1], s);
          sc[blk][jb] = s;
        }
      }
      bf16x8 pf[2];
#pragma unroll
      for (int jb = 0; jb < 2; ++jb) {
#pragma unroll
        for (int r = 0; r < 4; ++r) {
          pf[jb][r]     = (__bf16)ex2(sc[0][jb][r] * SC2_);
          pf[jb][4 + r] = (__bf16)ex2(sc[1][jb][r] * SC2_);
        }
        lacc[jb] = mfma16(ones, pf[jb], lacc[jb]);
      }
#pragma unroll
      for (int mb = 0; mb < 4; ++mb) {
        int row = mb * 16 + l15;
        bf16x8 vf = *(const bf16x8*)(Vs + chunk * 2048 + row * 32 + (g ^ swz(row)) * 8);
#pragma unroll
        for (int jb = 0; jb < 2; ++jb)
          acc[mb][jb] = mfma16(vf, pf[jb], acc[mb][jb]);
      }
    }
    __syncthreads();
  }

  // every lane holds l for its own q column in lacc[jb][0]
  if (lane < 16) {
#pragma unroll
    for (int jb = 0; jb < 2; ++jb)
      Lsum[(size_t)bh * S_ + q0 + w * 32 + jb * 16 + lane] = lacc[jb][0];
  }

  const int bb = bh >> 4, h = bh & 15;
#pragma unroll
  for (int jb = 0; jb < 2; ++jb) {
    float invl = 1.0f / lacc[jb][0];
    int q = q0 + w * 32 + jb * 16 + l15;
#pragma unroll
    for (int mb = 0; mb < 4; ++mb) {
      int d = mb * 16 + (g << 2);
      bf16x4 pk;
#pragma unroll
      for (int r = 0; r < 4; ++r) pk[r] = (__bf16)(acc[mb][jb][r] * invl);
      *(bf16x4*)(Ctx + ((size_t)bb * S_ + q) * E_ + h * 64 + d) = pk;
    }
  }
}

// ---------------- attn mean over heads (S^T recompute) ----------------
__global__ __launch_bounds__(256, 4) void attn_mean(const __bf16* __restrict__ Qb,
                                                    const __bf16* __restrict__ Kb,
                                                    const float* __restrict__ Lsum,
                                                    float* __restrict__ meanout) {
  __shared__ __attribute__((aligned(16))) __bf16 Qs[2 * 128 * 32];
  __shared__ __attribute__((aligned(16))) __bf16 Ks2[2 * 128 * 32];
  const int k0 = blockIdx.x * 128, q0 = blockIdx.y * 128, bI = blockIdx.z;
  const int t = threadIdx.x, lane = t & 63, w = t >> 6;
  const int l15 = lane & 15, g = lane >> 4;
  const int ksel = 8 * (l15 >> 2) + (l15 & 3);

  f32x4 macc[4][2][2] = {}; // [chunk][blk][jb]

  for (int h = 0; h < H_; ++h) {
    const size_t bh = (size_t)bI * H_ + h;
    const __bf16* Qh = Qb + bh * S_ * D_;
    const __bf16* Kh = Kb + bh * S_ * D_;
#pragma unroll
    for (int i = 0; i < 4; ++i) {
      int c = t + i * 256;
      int sub = c >> 9, rem = c & 511, row = rem >> 2, kc = rem & 3;
      int sl = kc ^ swz(row);
      load_lds16(Qh + (size_t)(q0 + row) * D_ + sub * 32 + sl * 8, (void*)(Qs + c * 8));
      load_lds16(Kh + (size_t)(k0 + row) * D_ + sub * 32 + sl * 8, (void*)(Ks2 + c * 8));
    }
    float invl[2];
#pragma unroll
    for (int jb = 0; jb < 2; ++jb)
      invl[jb] = 1.0f / Lsum[bh * S_ + q0 + w * 32 + jb * 16 + l15];
    __syncthreads();

    bf16x8 qf[2][2];
#pragma unroll
    for (int jb = 0; jb < 2; ++jb) {
      int row = w * 32 + jb * 16 + l15;
#pragma unroll
      for (int ks = 0; ks < 2; ++ks)
        qf[jb][ks] = *(const bf16x8*)(Qs + ks * 4096 + row * 32 + (g ^ swz(row)) * 8);
    }

#pragma unroll
    for (int chunk = 0; chunk < 4; ++chunk) {
#pragma unroll
      for (int blk = 0; blk < 2; ++blk) {
        int krow = chunk * 32 + 4 * blk + ksel;
        int so = (g ^ swz(krow)) * 8;
        bf16x8 kf0 = *(const bf16x8*)(Ks2 + krow * 32 + so);
        bf16x8 kf1 = *(const bf16x8*)(Ks2 + 4096 + krow * 32 + so);
#pragma unroll
        for (int jb = 0; jb < 2; ++jb) {
          f32x4 s = {};
          s = mfma16(kf0, qf[jb][0], s);
          s = mfma16(kf1, qf[jb][1], s);
#pragma unroll
          for (int r = 0; r < 4; ++r)
            macc[chunk][blk][jb][r] += ex2(s[r] * SC2_) * invl[jb];
        }
      }
    }
    __syncthreads();
  }

#pragma unroll
  for (int chunk = 0; chunk < 4; ++chunk)
#pragma unroll
    for (int blk = 0; blk < 2; ++blk)
#pragma unroll
      for (int jb = 0; jb < 2; ++jb) {
        int q = q0 + w * 32 + jb * 16 + l15;
        int kb = k0 + chunk * 32 + 8 * g + 4 * blk;
        f32x4 o;
#pragma unroll
        for (int r = 0; r < 4; ++r) o[r] = macc[chunk][blk][jb][r] * 0.0625f;
        *(f32x4*)(meanout + ((size_t)bI * S_ + q) * S_ + kb) = o;
      }
}

// ---------------- output projection GEMM ----------------
__global__ __launch_bounds__(256) void gemm_out(const __bf16* __restrict__ Ctx,
                                                const __bf16* __restrict__ Wo,
                                                const float* __restrict__ bo,
                                                float* __restrict__ out) {
  __shared__ __attribute__((aligned(16))) __bf16 As[128 * 32];
  __shared__ __attribute__((aligned(16))) __bf16 Bs[128 * 32];
  const int m0 = blockIdx.x * 128, n0 = blockIdx.y * 128;
  const int t = threadIdx.x, lane = t & 63, w = t >> 6;
  const int wm = w >> 1, wn = w & 1;
  const int l15 = lane & 15, g = lane >> 4;

  f32x4 acc[4][4] = {};

  for (int kk = 0; kk < E_; kk += 32) {
#pragma unroll
    for (int i = 0; i < 2; ++i) {
      int c = t + i * 256;
      int row = c >> 2, kc = c & 3;
      int sl = kc ^ swz(row);
      load_lds16(Ctx + (size_t)(m0 + row) * E_ + kk + sl * 8, (void*)(As + c * 8));
      load_lds16(Wo + (size_t)(n0 + row) * E_ + kk + sl * 8, (void*)(Bs + c * 8));
    }
    __syncthreads();
    bf16x8 a[4], b[4];
#pragma unroll
    for (int i = 0; i < 4; ++i) {
      int row = wm * 64 + i * 16 + l15;
      a[i] = *(const bf16x8*)(As + row * 32 + (g ^ swz(row)) * 8);
    }
#pragma unroll
    for (int j = 0; j < 4; ++j) {
      int row = wn * 64 + j * 16 + l15;
      b[j] = *(const bf16x8*)(Bs + row * 32 + (g ^ swz(row)) * 8);
    }
#pragma unroll
    for (int i = 0; i < 4; ++i)
#pragma unroll
      for (int j = 0; j < 4; ++j)
        acc[i][j] = mfma16(a[i], b[j], acc[i][j]);
    __syncthreads();
  }

#pragma unroll
  for (int i = 0; i < 4; ++i) {
    int mloc = wm * 64 + i * 16 + (g << 2);
#pragma unroll
    for (int j = 0; j < 4; ++j) {
      int n = n0 + wn * 64 + j * 16 + l15;
      float bs = bo[n];
#pragma unroll
      for (int r = 0; r < 4; ++r)
        out[(size_t)(m0 + mloc + r) * E_ + n] = acc[i][j][r] + bs;
    }
  }
}

extern "C" void kernel_launch(void* const* d_in, const int* in_sizes, int n_in,
                              void* d_out, int out_size, void* d_ws, size_t ws_size,
                              hipStream_t stream) {
  if (ws_size < WS_NEED) {
    hipMemsetAsync(d_out, 0, (size_t)out_size * sizeof(float), stream);
    return;
  }

  const float* q  = (const float*)d_in[0];
  const float* k  = (const float*)d_in[1];
  const float* v  = (const float*)d_in[2];
  const float* Wq = (const float*)d_in[3];
  const float* bq = (const float*)d_in[4];
  const float* Wk = (const float*)d_in[5];
  const float* bk = (const float*)d_in[6];
  const float* Wv = (const float*)d_in[7];
  const float* bv = (const float*)d_in[8];
  const float* Wo = (const float*)d_in[9];
  const float* bo = (const float*)d_in[10];

  char* ws = (char*)d_ws;
  __bf16* Xb  = (__bf16*)(ws + XB_OFF);
  __bf16* Wb  = (__bf16*)(ws + WB_OFF);
  __bf16* Qb  = (__bf16*)(ws + QB_OFF);
  __bf16* Kb  = (__bf16*)(ws + KB_OFF);
  __bf16* Vt  = (__bf16*)(ws + VT_OFF);
  __bf16* Ctx = (__bf16*)(ws + CTX_OFF);
  float*  Ls  = (float*)(ws + LS_OFF);

  float* out0 = (float*)d_out;
  float* out1 = (float*)d_out + (size_t)N_ * E_;

  conv_x<<<dim3(N_ * E_ / 4 / 256, 3), 256, 0, stream>>>(q, k, v, Xb);
  conv_w<<<dim3(E_ * E_ / 4 / 256, 4), 256, 0, stream>>>(Wq, Wk, Wv, Wo, Wb);
  gemm_qkv<<<dim3(N_ / 128, E_ / 128, 3), 256, 0, stream>>>(Xb, Wb, bq, bk, bv, Qb, Kb, Vt);
  attn_pv<<<dim3(S_ / 128, B_ * H_), 256, 0, stream>>>(Qb, Kb, Vt, Ls, Ctx);
  attn_mean<<<dim3(S_ / 128, S_ / 128, B_), 256, 0, stream>>>(Qb, Kb, Ls, out1);
  gemm_out<<<dim3(N_ / 128, E_ / 128), 256, 0, stream>>>(Ctx, Wb + 3 * (size_t)E_ * E_, bo, out0);
}